// Round 3
// baseline (183.669 us; speedup 1.0000x reference)
//
#include <hip/hip_runtime.h>
#include <hip/hip_cooperative_groups.h>

namespace cg = cooperative_groups;

// Problem constants
//   N=16 samples, C=256 content channels, S=512 style channels, HW=64x64
//
// Algebraic reduction of the reference:
//   k[n][3][3]  = conv(style[n], dw_w) + dw_b               (9 scalars / sample)
//   s_d[n][c]   = mean over 4x4 of style[n][c]
//   pw1[n]      = s_d[n] . pw_kn_w + pw_kn_b                (1 scalar / sample)
//   bias[n][o]  = s_d[n] . pw_bias_w[o] + pw_bias_b[o]
//   Xs[n][h][w] = sum_c content[n][c][h][w]                 (channel sum)
//   D[n][h][w]  = 3x3 reflect-pad conv of Xs with k[n]
//   out[n][o][h][w] = 256*pw1[n]*D[n][h][w] + bias[n][o]
//
// Single cooperative kernel, 512 blocks x 256 threads (2 blocks/CU co-resident):
//   phase 1: channel-sum partials Xp (all blocks) + style stats (blocks 0-15)
//   phase 2: 3x3 reflect conv -> E = scale*D (blocks 0-15)
//   phase 3: out[n][o][p] = E[n][p] + bias[n][o] (all blocks)

// workspace layout (floats)
#define OFF_SCALE 0                         // 16      : 256*pw1[n]
#define OFF_K     16                        // 16*9    : k[n][9]
#define OFF_BIAS  160                       // 16*256  : bias[n][o]
#define OFF_XP    4256                      // 16*8*4096 : channel-sum partials
#define OFF_E     (4256 + 16*8*4096)        // 16*4096 : E[n][p] = scale*D

__global__ __launch_bounds__(256, 2) void ada_fused(
    const float* __restrict__ style,      // (16,512,4,4)
    const float* __restrict__ content,    // (16,256,64,64)
    const float* __restrict__ dw_w,       // (1,512,2,2)
    const float* __restrict__ dw_b,       // (1,)
    const float* __restrict__ pw_kn_w,    // (1,512,1,1)
    const float* __restrict__ pw_kn_b,    // (1,)
    const float* __restrict__ pw_bias_w,  // (256,512,1,1)
    const float* __restrict__ pw_bias_b,  // (256,)
    float* __restrict__ ws,
    float4* __restrict__ out)
{
    const int bid = blockIdx.x;           // 512
    const int t   = threadIdx.x;          // 256

    __shared__ float sd[512];
    __shared__ float red[4][10];
    __shared__ float Xs[64][64];

    cg::grid_group grid = cg::this_grid();

    // ================= phase 1: channel-sum partials (all 512 blocks) ======
    {
        const int n  = bid >> 5;          // 16 samples
        const int r  = bid & 31;
        const int g  = r >> 2;            // 8 groups of 32 channels
        const int pt = r & 3;             // 4 spatial quarters
        const int p4 = pt * 256 + t;      // float4 index in 64x64 plane [0,1024)

        const float4* src = (const float4*)content
                          + ((size_t)(n * 256 + g * 32)) * 1024 + p4;
        float4 a = make_float4(0.f, 0.f, 0.f, 0.f);
#pragma unroll 8
        for (int c = 0; c < 32; ++c) {
            float4 v = src[(size_t)c * 1024];
            a.x += v.x; a.y += v.y; a.z += v.z; a.w += v.w;
        }
        ((float4*)(ws + OFF_XP))[((size_t)(n * 8 + g)) * 1024 + p4] = a;
    }

    // ================= phase 1b: style stats (blocks 0-15) =================
    if (bid < 16) {
        const int n = bid;

        float acc[10];
#pragma unroll
        for (int j = 0; j < 10; ++j) acc[j] = 0.f;

#pragma unroll
        for (int cc = 0; cc < 2; ++cc) {
            const int c = t + cc * 256;
            const float4* sp = (const float4*)(style + ((size_t)n * 512 + c) * 16);
            float v[16];
#pragma unroll
            for (int q = 0; q < 4; ++q) {
                float4 f = sp[q];
                v[q*4+0] = f.x; v[q*4+1] = f.y; v[q*4+2] = f.z; v[q*4+3] = f.w;
            }
            float sum = 0.f;
#pragma unroll
            for (int q = 0; q < 16; ++q) sum += v[q];
            const float sdc = sum * 0.0625f;   // mean over 4x4
            sd[c] = sdc;

            const float* w = dw_w + c * 4;     // [a*2+b]
            const float w00 = w[0], w01 = w[1], w10 = w[2], w11 = w[3];
#pragma unroll
            for (int ki = 0; ki < 3; ++ki)
#pragma unroll
                for (int kj = 0; kj < 3; ++kj)
                    acc[ki*3+kj] += v[ki*4 + kj]       * w00
                                  + v[ki*4 + kj + 1]   * w01
                                  + v[(ki+1)*4 + kj]   * w10
                                  + v[(ki+1)*4 + kj+1] * w11;
            acc[9] += sdc * pw_kn_w[c];
        }

        // wave(64)-level butterfly reduce of the 10 partials
#pragma unroll
        for (int off = 32; off >= 1; off >>= 1)
#pragma unroll
            for (int j = 0; j < 10; ++j)
                acc[j] += __shfl_down(acc[j], off, 64);

        if ((t & 63) == 0) {
#pragma unroll
            for (int j = 0; j < 10; ++j) red[t >> 6][j] = acc[j];
        }
        __syncthreads();

        if (t < 10) {
            const float s = red[0][t] + red[1][t] + red[2][t] + red[3][t];
            if (t < 9) ws[OFF_K + n * 9 + t] = s + dw_b[0];
            else       ws[OFF_SCALE + n]     = 256.f * (s + pw_kn_b[0]);
        }

        // bias[n][t] = sd . pw_bias_w[t] + pw_bias_b[t]
        float a2 = 0.f;
        const float4* wrow = (const float4*)(pw_bias_w + (size_t)t * 512);
#pragma unroll 4
        for (int c4 = 0; c4 < 128; ++c4) {
            float4 f = wrow[c4];
            a2 += sd[c4*4+0]*f.x + sd[c4*4+1]*f.y + sd[c4*4+2]*f.z + sd[c4*4+3]*f.w;
        }
        ws[OFF_BIAS + n * 256 + t] = a2 + pw_bias_b[t];
    }

    grid.sync();

    // ================= phase 2: 3x3 reflect conv (blocks 0-15) =============
    if (bid < 16) {
        const int n = bid;

        const float* Xp = ws + OFF_XP + (size_t)n * 8 * 4096;
#pragma unroll
        for (int rr = 0; rr < 16; ++rr) {
            const int p = rr * 256 + t;
            float s = 0.f;
#pragma unroll
            for (int g = 0; g < 8; ++g) s += Xp[g * 4096 + p];
            Xs[p >> 6][p & 63] = s;
        }

        float k[9];
#pragma unroll
        for (int j = 0; j < 9; ++j) k[j] = ws[OFF_K + n * 9 + j];
        const float scale = ws[OFF_SCALE + n];
        __syncthreads();

#pragma unroll
        for (int rr = 0; rr < 16; ++rr) {
            const int p = rr * 256 + t, h = p >> 6, w = p & 63;
            float d = 0.f;
#pragma unroll
            for (int ki = 0; ki < 3; ++ki) {
                int hh = h + ki - 1;
                hh = hh < 0 ? 1 : (hh > 63 ? 62 : hh);   // reflect (no edge repeat)
#pragma unroll
                for (int kj = 0; kj < 3; ++kj) {
                    int wwi = w + kj - 1;
                    wwi = wwi < 0 ? 1 : (wwi > 63 ? 62 : wwi);
                    d += k[ki*3+kj] * Xs[hh][wwi];
                }
            }
            ws[OFF_E + n * 4096 + p] = scale * d;
        }
    }

    grid.sync();

    // ================= phase 3: broadcast-add output (all 512 blocks) ======
    {
        const int n = bid >> 5;               // 32 blocks per sample, 8 planes each
        const float4* En = (const float4*)(ws + OFF_E) + (size_t)n * 1024;

        float4 e[4];
#pragma unroll
        for (int i = 0; i < 4; ++i) e[i] = En[i * 256 + t];

        float4* o = out + (size_t)bid * 8192;
#pragma unroll
        for (int pl = 0; pl < 8; ++pl) {
            const float b = ws[OFF_BIAS + bid * 8 + pl];   // global plane = n*256+o
#pragma unroll
            for (int i = 0; i < 4; ++i) {
                float4 v = e[i];
                o[pl * 1024 + i * 256 + t] =
                    make_float4(v.x + b, v.y + b, v.z + b, v.w + b);
            }
        }
    }
}

// ---------------------------------------------------------------- launch
extern "C" void kernel_launch(void* const* d_in, const int* in_sizes, int n_in,
                              void* d_out, int out_size, void* d_ws, size_t ws_size,
                              hipStream_t stream)
{
    const float* style     = (const float*)d_in[0];
    const float* content   = (const float*)d_in[1];
    const float* dw_w      = (const float*)d_in[2];
    const float* dw_b      = (const float*)d_in[3];
    const float* pw_kn_w   = (const float*)d_in[4];
    const float* pw_kn_b   = (const float*)d_in[5];
    const float* pw_bias_w = (const float*)d_in[6];
    const float* pw_bias_b = (const float*)d_in[7];
    float*  ws  = (float*)d_ws;
    float4* out = (float4*)d_out;

    void* args[] = { (void*)&style, (void*)&content, (void*)&dw_w, (void*)&dw_b,
                     (void*)&pw_kn_w, (void*)&pw_kn_b, (void*)&pw_bias_w,
                     (void*)&pw_bias_b, (void*)&ws, (void*)&out };

    hipLaunchCooperativeKernel((const void*)ada_fused,
                               dim3(512), dim3(256), args, 0, stream);
}

// Round 4
// 47.111 us; speedup vs baseline: 3.8986x; 3.8986x over previous
//
#include <hip/hip_runtime.h>

// Problem constants
//   N=16 samples, C=256 content channels, S=512 style channels, HW=64x64
//
// Algebraic reduction of the reference:
//   k[n][3][3]  = conv(style[n], dw_w) + dw_b               (9 scalars / sample)
//   s_d[n][c]   = mean over 4x4 of style[n][c]
//   pw1[n]      = s_d[n] . pw_kn_w + pw_kn_b                (1 scalar / sample)
//   bias[n][o]  = s_d[n] . pw_bias_w[o] + pw_bias_b[o]
//   Xs[n][h][w] = sum_c content[n][c][h][w]                 (channel sum)
//   D[n][h][w]  = 3x3 reflect-pad conv of Xs with k[n]
//   out[n][o][h][w] = 256*pw1[n]*D[n][h][w] + bias[n][o]
//
// Two plain dispatches (no grid sync — round 3's cooperative version ran at
// 8% of HBM peak due to 2-blocks/CU cap + 512-block spin barrier):
//   K1: style stats (blocks 0-15) + channel-sum partials Xp (blocks 16-527)
//   K2: 1024 blocks; each rebuilds Xs[n] from Xp (L2-resident, conv is cheap
//       so recomputing it per block beats a third dispatch), 3x3 reflect conv
//       into LDS, then streams 4 output planes (E + bias).

// workspace layout (floats)
#define OFF_SCALE 0                         // 16      : 256*pw1[n]
#define OFF_K     16                        // 16*9    : k[n][9]
#define OFF_BIAS  160                       // 16*256  : bias[n][o]
#define OFF_XP    4256                      // 16*8*4096 : channel-sum partials

// ---------------------------------------------------------------- kernel 1
__global__ __launch_bounds__(256, 2) void ada_front(
    const float* __restrict__ style,      // (16,512,4,4)
    const float* __restrict__ content,    // (16,256,64,64)
    const float* __restrict__ dw_w,       // (1,512,2,2)
    const float* __restrict__ dw_b,       // (1,)
    const float* __restrict__ pw_kn_w,    // (1,512,1,1)
    const float* __restrict__ pw_kn_b,    // (1,)
    const float* __restrict__ pw_bias_w,  // (256,512,1,1)
    const float* __restrict__ pw_bias_b,  // (256,)
    float* __restrict__ ws)
{
    const int t = threadIdx.x;
    __shared__ float sd[512];
    __shared__ float red[4][10];

    if (blockIdx.x >= 16) {
        // ---- channel-sum partials (round-1 proven indexing)
        // Xp[n][g][p] = sum_{c in 32-ch group g} content[n][c][p]
        const int b  = blockIdx.x - 16;   // 512 blocks
        const int n  = b >> 5;            // 16 samples
        const int g  = (b >> 2) & 7;      // 8 groups of 32 channels
        const int pt = b & 3;             // 4 spatial quarters
        const int p4 = pt * 256 + t;      // float4 index in 64x64 plane [0,1024)

        const float4* src = (const float4*)content
                          + ((size_t)(n * 256 + g * 32)) * 1024 + p4;
        float4 a = make_float4(0.f, 0.f, 0.f, 0.f);
#pragma unroll 8
        for (int c = 0; c < 32; ++c) {
            float4 v = src[(size_t)c * 1024];
            a.x += v.x; a.y += v.y; a.z += v.z; a.w += v.w;
        }
        ((float4*)(ws + OFF_XP))[((size_t)(n * 8 + g)) * 1024 + p4] = a;
        return;
    }

    // ---- per-sample style stats
    const int n = blockIdx.x;

    float acc[10];
#pragma unroll
    for (int j = 0; j < 10; ++j) acc[j] = 0.f;

#pragma unroll
    for (int cc = 0; cc < 2; ++cc) {
        const int c = t + cc * 256;
        const float4* sp = (const float4*)(style + ((size_t)n * 512 + c) * 16);
        float v[16];
#pragma unroll
        for (int q = 0; q < 4; ++q) {
            float4 f = sp[q];
            v[q*4+0] = f.x; v[q*4+1] = f.y; v[q*4+2] = f.z; v[q*4+3] = f.w;
        }
        float sum = 0.f;
#pragma unroll
        for (int q = 0; q < 16; ++q) sum += v[q];
        const float sdc = sum * 0.0625f;   // mean over 4x4
        sd[c] = sdc;

        const float* w = dw_w + c * 4;     // [a*2+b]
        const float w00 = w[0], w01 = w[1], w10 = w[2], w11 = w[3];
#pragma unroll
        for (int ki = 0; ki < 3; ++ki)
#pragma unroll
            for (int kj = 0; kj < 3; ++kj)
                acc[ki*3+kj] += v[ki*4 + kj]       * w00
                              + v[ki*4 + kj + 1]   * w01
                              + v[(ki+1)*4 + kj]   * w10
                              + v[(ki+1)*4 + kj+1] * w11;
        acc[9] += sdc * pw_kn_w[c];
    }

    // wave(64)-level butterfly reduce of the 10 partials
#pragma unroll
    for (int off = 32; off >= 1; off >>= 1)
#pragma unroll
        for (int j = 0; j < 10; ++j)
            acc[j] += __shfl_down(acc[j], off, 64);

    if ((t & 63) == 0) {
#pragma unroll
        for (int j = 0; j < 10; ++j) red[t >> 6][j] = acc[j];
    }
    __syncthreads();

    if (t < 10) {
        const float s = red[0][t] + red[1][t] + red[2][t] + red[3][t];
        if (t < 9) ws[OFF_K + n * 9 + t] = s + dw_b[0];
        else       ws[OFF_SCALE + n]     = 256.f * (s + pw_kn_b[0]);
    }

    // bias[n][t] = sd . pw_bias_w[t] + pw_bias_b[t]
    float a2 = 0.f;
    const float4* wrow = (const float4*)(pw_bias_w + (size_t)t * 512);
#pragma unroll 4
    for (int c4 = 0; c4 < 128; ++c4) {
        float4 f = wrow[c4];
        a2 += sd[c4*4+0]*f.x + sd[c4*4+1]*f.y + sd[c4*4+2]*f.z + sd[c4*4+3]*f.w;
    }
    ws[OFF_BIAS + n * 256 + t] = a2 + pw_bias_b[t];
}

// ---------------------------------------------------------------- kernel 2
// 1024 blocks: block (n, s) rebuilds Xs[n] from Xp (L2-resident), does the
// 3x3 reflect conv into LDS (E = scale*D), then writes planes s*4 .. s*4+3.
__global__ __launch_bounds__(256, 2) void ada_back(
    const float* __restrict__ ws, float4* __restrict__ out)
{
    const int bid = blockIdx.x;     // 1024
    const int n   = bid >> 6;       // 16 samples
    const int s   = bid & 63;       // plane group: planes s*4 .. s*4+3
    const int t   = threadIdx.x;

    __shared__ float Xs[4096];      // channel-sum image, row-major 64x64
    __shared__ float E[4096];       // scale * conv(Xs)

    // ---- Xs = sum of the 8 group partials
    const float4* Xp = (const float4*)(ws + OFF_XP) + (size_t)n * 8 * 1024;
#pragma unroll
    for (int i = 0; i < 4; ++i) {
        const int p4 = i * 256 + t;
        float4 a = Xp[p4];
#pragma unroll
        for (int g = 1; g < 8; ++g) {
            float4 v = Xp[g * 1024 + p4];
            a.x += v.x; a.y += v.y; a.z += v.z; a.w += v.w;
        }
        ((float4*)Xs)[p4] = a;
    }

    float k[9];
#pragma unroll
    for (int j = 0; j < 9; ++j) k[j] = ws[OFF_K + n * 9 + j];
    const float scale = ws[OFF_SCALE + n];
    __syncthreads();

    // ---- 3x3 reflect conv (reflect = no edge repeat: -1 -> 1, 64 -> 62)
#pragma unroll
    for (int r = 0; r < 16; ++r) {
        const int p = r * 256 + t, h = p >> 6, w = p & 63;
        float d = 0.f;
#pragma unroll
        for (int ki = 0; ki < 3; ++ki) {
            int hh = h + ki - 1;
            hh = hh < 0 ? 1 : (hh > 63 ? 62 : hh);
#pragma unroll
            for (int kj = 0; kj < 3; ++kj) {
                int wwi = w + kj - 1;
                wwi = wwi < 0 ? 1 : (wwi > 63 ? 62 : wwi);
                d += k[ki*3+kj] * Xs[hh * 64 + wwi];
            }
        }
        E[p] = scale * d;
    }
    __syncthreads();

    // ---- stream 4 output planes: out[n][o][p] = E[p] + bias[n][o]
    const float4* E4 = (const float4*)E;
    float4* o = out + ((size_t)(n * 256 + s * 4)) * 1024;
#pragma unroll
    for (int pl = 0; pl < 4; ++pl) {
        const float b = ws[OFF_BIAS + n * 256 + s * 4 + pl];  // block-uniform
#pragma unroll
        for (int i = 0; i < 4; ++i) {
            float4 v = E4[i * 256 + t];
            o[(size_t)pl * 1024 + i * 256 + t] =
                make_float4(v.x + b, v.y + b, v.z + b, v.w + b);
        }
    }
}

// ---------------------------------------------------------------- launch
extern "C" void kernel_launch(void* const* d_in, const int* in_sizes, int n_in,
                              void* d_out, int out_size, void* d_ws, size_t ws_size,
                              hipStream_t stream)
{
    const float* style     = (const float*)d_in[0];
    const float* content   = (const float*)d_in[1];
    const float* dw_w      = (const float*)d_in[2];
    const float* dw_b      = (const float*)d_in[3];
    const float* pw_kn_w   = (const float*)d_in[4];
    const float* pw_kn_b   = (const float*)d_in[5];
    const float* pw_bias_w = (const float*)d_in[6];
    const float* pw_bias_b = (const float*)d_in[7];
    float*  ws  = (float*)d_ws;
    float4* out = (float4*)d_out;

    ada_front<<<16 + 512, 256, 0, stream>>>(style, content, dw_w, dw_b,
                                            pw_kn_w, pw_kn_b,
                                            pw_bias_w, pw_bias_b, ws);
    ada_back <<<1024,     256, 0, stream>>>(ws, out);
}